// Round 16
// baseline (206.627 us; speedup 1.0000x reference)
//
#include <hip/hip_runtime.h>
#include <hip/hip_bf16.h>

// MHA fused pipeline: B=4, S=2048, D=1024, H=16, HD=64.
//   k0: fused cvt: x -> xb bf16, w_qkv -> wqkv_b bf16 (d_out scratch)
//   k1: qkv = xb @ wqkv_b^T + b_qkv -> SCATTER to Q (pre-scaled), K, VT planes
//   k2: flash attention, 32x32x16 MFMA, in-register P via explicit
//       shfl_xor(32)+select partner exchange (permlane semantics ambiguous ->
//       R15 failure; this is transparent), K/VT via global_load_lds
//       (pre-swizzled source), no-max softmax
//   k0c: w_o -> bf16 into Q-plane (dead after attn)
//   k3: out = vals @ wo_b^T + b_o
// ws: [xb|vals 16.8MB][Q|wo_b 16.8][K 16.8][VT 16.8] = 67.1 MB.

typedef __attribute__((ext_vector_type(4))) float f32x4;
typedef __attribute__((ext_vector_type(16))) float f32x16;
typedef __attribute__((ext_vector_type(8))) short s16x8;
typedef __attribute__((ext_vector_type(4))) short s16x4;
typedef __attribute__((ext_vector_type(2))) unsigned u32x2;
typedef __attribute__((ext_vector_type(4))) unsigned u32x4;

constexpr size_t PART_ELEMS = (size_t)8192 * 1024;  // one bf16 plane

__device__ __forceinline__ unsigned short f2bf(float f) {
  __hip_bfloat16 h = __float2bfloat16(f);
  unsigned short u;
  __builtin_memcpy(&u, &h, 2);
  return u;
}
__device__ __forceinline__ unsigned pack2bf(float a, float b) {
  return (unsigned)f2bf(a) | ((unsigned)f2bf(b) << 16);
}
__device__ __forceinline__ float fexp2(float x) {
#if __has_builtin(__builtin_amdgcn_exp2f)
  return __builtin_amdgcn_exp2f(x);
#else
  float r; asm("v_exp_f32 %0, %1" : "=v"(r) : "v"(x)); return r;
#endif
}
// async global->LDS, 16B per lane. LDS dest is wave-uniform base + lane*16.
__device__ __forceinline__ void gload_lds16(const void* g, void* l) {
  __builtin_amdgcn_global_load_lds(
      (const __attribute__((address_space(1))) unsigned*)g,
      (__attribute__((address_space(3))) unsigned*)l, 16, 0, 0);
}
// XOR-swizzled short-index into a [rows][64]-short tile.
__device__ __forceinline__ int swzs(int row, int col) {
  return row * 64 + (((col >> 3) ^ (row & 7)) << 3) + (col & 7);
}

// ---- k0: fused fp32 -> bf16 convert for x (4096 blocks) + w_qkv (1536) ----
__global__ __launch_bounds__(256) void cvt2_kernel(
    const float* __restrict__ a, unsigned short* __restrict__ oa,
    const float* __restrict__ b, unsigned short* __restrict__ ob) {
  const int bid = blockIdx.x;
  const float* in;
  unsigned short* out;
  size_t i;
  if (bid < 4096) {
    in = a; out = oa; i = ((size_t)bid * 256 + threadIdx.x) * 8;
  } else {
    in = b; out = ob; i = ((size_t)(bid - 4096) * 256 + threadIdx.x) * 8;
  }
  f32x4 v0 = *reinterpret_cast<const f32x4*>(in + i);
  f32x4 v1 = *reinterpret_cast<const f32x4*>(in + i + 4);
  u32x4 pk;
  pk.x = pack2bf(v0.x, v0.y); pk.y = pack2bf(v0.z, v0.w);
  pk.z = pack2bf(v1.x, v1.y); pk.w = pack2bf(v1.z, v1.w);
  *reinterpret_cast<u32x4*>(out + i) = pk;
}

// ---- plain fp32 -> bf16 convert (w_o) ----
__global__ __launch_bounds__(256) void cvt_kernel(const float* __restrict__ in,
                                                  unsigned short* __restrict__ out) {
  const size_t i = ((size_t)blockIdx.x * 256 + threadIdx.x) * 8;
  f32x4 v0 = *reinterpret_cast<const f32x4*>(in + i);
  f32x4 v1 = *reinterpret_cast<const f32x4*>(in + i + 4);
  u32x4 pk;
  pk.x = pack2bf(v0.x, v0.y); pk.y = pack2bf(v0.z, v0.w);
  pk.z = pack2bf(v1.x, v1.y); pk.w = pack2bf(v1.z, v1.w);
  *reinterpret_cast<u32x4*>(out + i) = pk;
}

// C[M,N] = A[M,K](bf16) @ Bw[N,K](bf16)^T + bias.  (unchanged from R14)
template <bool SCATTER>
__global__ __launch_bounds__(256) void gemm_bb(
    const unsigned short* __restrict__ A, const unsigned short* __restrict__ Bw,
    const float* __restrict__ bias, void* __restrict__ Cptr,
    int M, int N, int K) {
  __shared__ short lds_a[128 * 64];
  __shared__ short lds_b[128 * 64];
  const int t = threadIdx.x;
  const int l = t & 63;
  const int w = t >> 6;
  const int id = blockIdx.x;
  const int xcd = id & 7;
  const int rr = id >> 3;
  const int bm = (xcd * 8 + (rr & 7)) * 128;
  const int bn = (rr >> 3) * 128;
  const int wr = (w >> 1) * 64;
  const int wc = (w & 1) * 64;
  const int lr = l & 15;
  const int lkh = l >> 4;

  f32x4 acc[4][4] = {};

  const int c8 = l >> 3;
  const int gcol = ((l & 7) ^ c8) * 8;

  for (int k0 = 0; k0 < K; k0 += 64) {
    const unsigned short* as = &A[(size_t)(bm + w * 32 + c8) * K + k0 + gcol];
    const unsigned short* bs = &Bw[(size_t)(bn + w * 32 + c8) * K + k0 + gcol];
#pragma unroll
    for (int c = 0; c < 4; ++c) {
      gload_lds16(as + (size_t)(c * 8) * K, &lds_a[(w * 32 + c * 8) * 64]);
      gload_lds16(bs + (size_t)(c * 8) * K, &lds_b[(w * 32 + c * 8) * 64]);
    }
    __syncthreads();

#pragma unroll
    for (int ki = 0; ki < 2; ++ki) {
      s16x8 af[4], bfr[4];
#pragma unroll
      for (int mt = 0; mt < 4; ++mt) {
        const int row = wr + mt * 16 + lr;
        af[mt] = *reinterpret_cast<const s16x8*>(
            &lds_a[row * 64 + ((((ki << 2) + lkh) ^ (lr & 7)) << 3)]);
      }
#pragma unroll
      for (int nt = 0; nt < 4; ++nt) {
        const int row = wc + nt * 16 + lr;
        bfr[nt] = *reinterpret_cast<const s16x8*>(
            &lds_b[row * 64 + ((((ki << 2) + lkh) ^ (lr & 7)) << 3)]);
      }
#pragma unroll
      for (int mt = 0; mt < 4; ++mt)
#pragma unroll
        for (int nt = 0; nt < 4; ++nt)
          acc[mt][nt] = __builtin_amdgcn_mfma_f32_16x16x32_bf16(af[mt], bfr[nt], acc[mt][nt], 0, 0, 0);
    }
    __syncthreads();
  }

  if (SCATTER) {
    unsigned short* W = (unsigned short*)Cptr;
    const int s0 = (bm & 2047) + wr + (l >> 4) * 4;
    const int batch = bm >> 11;
#pragma unroll
    for (int nt = 0; nt < 4; ++nt) {
      const int col = bn + wc + nt * 16 + lr;
      const int h = col / 192;
      const int rem = col - h * 192;
      const int part = rem >> 6;          // 0=Q 1=K 2=V
      const int d = rem & 63;
      const size_t bh = (size_t)batch * 16 + h;
      const float bv = bias[col];
      unsigned short* base;
      int stride;
      float scale;
      if (part == 2) {
        base = W + 2 * PART_ELEMS + (bh * 64 + d) * 2048;   // VT[bh][d][s]
        stride = 1;
        scale = 1.0f;
      } else {
        base = W + (size_t)part * PART_ELEMS + bh * 2048 * 64 + d;  // Q/K[bh][s][d]
        stride = 64;
        scale = (part == 0) ? 0.1803368801f : 1.0f;         // 0.125*log2e on Q
      }
      unsigned short* p = base + (size_t)s0 * stride;
#pragma unroll
      for (int mt = 0; mt < 4; ++mt) {
        unsigned short* pm = p + mt * 16 * stride;
#pragma unroll
        for (int r = 0; r < 4; ++r)
          pm[r * stride] = f2bf((acc[mt][nt][r] + bv) * scale);
      }
    }
  } else {
    float* C = (float*)Cptr;
#pragma unroll
    for (int mt = 0; mt < 4; ++mt) {
#pragma unroll
      for (int nt = 0; nt < 4; ++nt) {
        const int col = bn + wc + nt * 16 + lr;
        const float bv = bias[col];
#pragma unroll
        for (int r = 0; r < 4; ++r) {
          const int row = bm + wr + mt * 16 + (l >> 4) * 4 + r;
          C[(size_t)row * N + col] = acc[mt][nt][r] + bv;
        }
      }
    }
  }
}

// Flash attention, 32x32x16 MFMA. Per wave: 32 q-rows (col dim), KV tile 64.
// Swapped QK^T: s_acc[c] = mfma32(K, Q) -> S^T[kv = c*32 + (r&3)+8*(r>>2)+4*hi]
// [q = w*32 + (l&31)]. All 32 kv values for ONE q live in-lane -> no-max
// softmax has zero cross-lane work in the loop. P^T B-fragments assembled
// in-register with EXPLICIT shfl_xor(32) + select (lane l <-> l^32 exchange;
// lo lane pf = [own kv{0,1},{2,3}, partner kv{4,5},{6,7}], hi lane pf =
// [partner kv{8,9},{10,11}, own kv{12,13},{14,15}] per K=16 slice).
// K/VT staged by global_load_lds (linear dest + pre-swizzled source).
// LDS 32 KB, no P buffer. Deferred l-reduce: one shfl_xor(32) at the end.
__global__ __launch_bounds__(512, 4) void attn_kernel(
    const unsigned short* __restrict__ ws, unsigned short* __restrict__ vals) {
  __shared__ short k_lds[2 * 64 * 64];
  __shared__ short vt_lds[2 * 64 * 64];
  const int t = threadIdx.x;
  const int l = t & 63;
  const int w = t >> 6;            // 0..7
  const int l31 = l & 31;
  const int hi = l >> 5;
  const int f = blockIdx.x;        // 0..511
  const int xcd = f & 7;
  const int j = f >> 3;
  const int bh = xcd * 8 + (j & 7);
  const int qt = j >> 3;           // 0..7
  const int b = bh >> 4;
  const int h = bh & 15;
  const unsigned short* Qh  = ws + (size_t)bh * (2048 * 64);
  const unsigned short* Kh  = ws + PART_ELEMS + (size_t)bh * (2048 * 64);
  const unsigned short* VTh = ws + 2 * PART_ELEMS + (size_t)bh * (64 * 2048);

  // staging: wave w owns tile rows w*8..w*8+7; lane covers row w*8+(l>>3),
  // 16B-unit (l&7) in LDS (linear), unit (l&7)^(row&7) on the global side.
  const int sr = l >> 3;
  const int gcu = (l & 7) ^ sr;
  const unsigned short* Ks = Kh + (size_t)(w * 8 + sr) * 64 + gcu * 8;
  const unsigned short* Vs = VTh + (size_t)(w * 8 + sr) * 2048 + gcu * 8;
  short* kd = &k_lds[w * 512];
  short* vd = &vt_lds[w * 512];

  // Q as B-operand: lane holds col q = w*32+l31, k = hi*8+j; 4 K-steps of 16
  s16x8 qf[4];
  {
    const unsigned short* qb = Qh + ((size_t)qt * 256 + w * 32 + l31) * 64 + hi * 8;
#pragma unroll
    for (int s = 0; s < 4; ++s)
      qf[s] = *reinterpret_cast<const s16x8*>(qb + s * 16);
  }

  gload_lds16(Ks, kd);
  gload_lds16(Vs, vd);
  __syncthreads();

  f32x16 o_acc[2] = {};
  float l_s = 0.f;

  for (int kt = 0; kt < 32; ++kt) {
    const int cur = kt & 1;
    if (kt + 1 < 32) {  // async prefetch into the other buffer
      gload_lds16(Ks + (size_t)(kt + 1) * 4096, kd + (cur ^ 1) * 4096);
      gload_lds16(Vs + (size_t)(kt + 1) * 64, vd + (cur ^ 1) * 4096);
    }
    const short* kb = &k_lds[cur * 4096];
    const short* vb = &vt_lds[cur * 4096];

    // ---- S^T = K Q^T : 2 kv-blocks x 4 K-steps of 32x32x16 ----
    f32x16 s_acc[2] = {};
#pragma unroll
    for (int c = 0; c < 2; ++c) {
      s16x8 kf[4];
#pragma unroll
      for (int s = 0; s < 4; ++s)
        kf[s] = *reinterpret_cast<const s16x8*>(&kb[swzs(c * 32 + l31, s * 16 + hi * 8)]);
      __builtin_amdgcn_s_setprio(1);
#pragma unroll
      for (int s = 0; s < 4; ++s)
        s_acc[c] = __builtin_amdgcn_mfma_f32_32x32x16_bf16(kf[s], qf[s], s_acc[c], 0, 0, 0);
      __builtin_amdgcn_s_setprio(0);
    }

    // ---- no-max softmax: P = exp2(s); pack pairs (kv r, r+1) ----
    // u[c][i]: i=0..7 -> kv pairs {4hi+0,1},{4hi+2,3},{8+4hi+0,1},{8+4hi+2,3},
    //                    {16+...},{24+...} within the c*32 block.
    unsigned u[2][8];
    float rs = 0.f;
#pragma unroll
    for (int c = 0; c < 2; ++c)
#pragma unroll
      for (int i = 0; i < 8; ++i) {
        const float p0 = fexp2(s_acc[c][2 * i]);
        const float p1 = fexp2(s_acc[c][2 * i + 1]);
        rs += p0 + p1;
        u[c][i] = pack2bf(p0, p1);
      }
    l_s += rs;

    // ---- O^T += V^T P^T : pf per K=16 slice via explicit partner exchange.
    // B-operand lane needs P^T[kv = ks*16 + hi*8 + j][q = w*32+l31], j=0..7:
    //   lo lane: kv 0..7  = own u[g+0],u[g+1] (kv 0-3) + partner u[g+0],u[g+1] (kv 4-7)
    //   hi lane: kv 8..15 = partner u[g+2],u[g+3] (kv 8-11) + own u[g+2],u[g+3] (kv 12-15)
#pragma unroll
    for (int ks = 0; ks < 4; ++ks) {
      const int c = ks >> 1;
      const int g = (ks & 1) * 4;
      const unsigned u0 = u[c][g + 0], u1 = u[c][g + 1];
      const unsigned u2 = u[c][g + 2], u3 = u[c][g + 3];
      const unsigned p0 = (unsigned)__shfl_xor((int)u0, 32);
      const unsigned p1 = (unsigned)__shfl_xor((int)u1, 32);
      const unsigned p2 = (unsigned)__shfl_xor((int)u2, 32);
      const unsigned p3 = (unsigned)__shfl_xor((int)u3, 32);
      u32x4 pw;
      pw.x = hi ? p2 : u0;
      pw.y = hi ? p3 : u1;
      pw.z = hi ? u2 : p0;
      pw.w = hi ? u3 : p1;
      const s16x8 pf = __builtin_bit_cast(s16x8, pw);
      s16x8 vf0 = *reinterpret_cast<const s16x8*>(&vb[swzs(l31, ks * 16 + hi * 8)]);
      s16x8 vf1 = *reinterpret_cast<const s16x8*>(&vb[swzs(32 + l31, ks * 16 + hi * 8)]);
      __builtin_amdgcn_s_setprio(1);
      o_acc[0] = __builtin_amdgcn_mfma_f32_32x32x16_bf16(vf0, pf, o_acc[0], 0, 0, 0);
      o_acc[1] = __builtin_amdgcn_mfma_f32_32x32x16_bf16(vf1, pf, o_acc[1], 0, 0, 0);
      __builtin_amdgcn_s_setprio(0);
    }
    __syncthreads();  // reads of cur done; prefetch into nxt drained (vmcnt)
  }

  // ---- epilogue: O^T[d = db*32 + (r&3)+8*(r>>2)+4*hi][q = w*32+l31] ----
  l_s += __shfl_xor(l_s, 32);
  const float inv = 1.0f / l_s;
  const size_t row = (size_t)b * 2048 + qt * 256 + w * 32 + l31;
  unsigned short* vout = vals + row * 1024 + h * 64 + 4 * hi;
#pragma unroll
  for (int db = 0; db < 2; ++db) {
#pragma unroll
    for (int g = 0; g < 4; ++g) {
      s16x4 o4;
#pragma unroll
      for (int r = 0; r < 4; ++r)
        o4[r] = (short)f2bf(o_acc[db][4 * g + r] * inv);
      *reinterpret_cast<s16x4*>(&vout[db * 32 + 8 * g]) = o4;
    }
  }
}

extern "C" void kernel_launch(void* const* d_in, const int* in_sizes, int n_in,
                              void* d_out, int out_size, void* d_ws, size_t ws_size,
                              hipStream_t stream) {
  const float* x     = (const float*)d_in[0];   // [4,2048,1024]
  const float* w_qkv = (const float*)d_in[1];   // [3072,1024]
  const float* b_qkv = (const float*)d_in[2];   // [3072]
  const float* w_o   = (const float*)d_in[3];   // [1024,1024]
  const float* b_o   = (const float*)d_in[4];   // [1024]
  float* out = (float*)d_out;                   // [4,2048,1024] fp32

  unsigned short* xb     = (unsigned short*)d_ws;   // x bf16; later: vals (aliased)
  unsigned short* planes = xb + PART_ELEMS;         // Q | K | VT planes
  unsigned short* wqkv_b = (unsigned short*)d_out;  // d_out scratch (read only by gemm1)
  unsigned short* wo_b   = planes;                  // Q-plane, dead after attn

  cvt2_kernel<<<5632, 256, 0, stream>>>(x, xb, w_qkv, wqkv_b);      // x + w_qkv -> bf16
  gemm_bb<true><<<1536, 256, 0, stream>>>(
      xb, wqkv_b, b_qkv, planes, 8192, 3072, 1024);                 // qkv + scatter
  attn_kernel<<<512, 512, 0, stream>>>(planes, xb);                 // vals -> xb
  cvt_kernel<<<512, 256, 0, stream>>>(w_o, wo_b);                   // w_o -> bf16 (Q-plane)
  gemm_bb<false><<<512, 256, 0, stream>>>(
      xb, wo_b, b_o, out, 8192, 1024, 1024);                        // out proj
}

// Round 17
// 202.621 us; speedup vs baseline: 1.0198x; 1.0198x over previous
//
#include <hip/hip_runtime.h>
#include <hip/hip_bf16.h>

// MHA fused pipeline: B=4, S=2048, D=1024, H=16, HD=64.
//   k0: fused cvt: x -> xb bf16, w_qkv -> wqkv_b bf16 (d_out scratch)
//   k1: qkv = xb @ wqkv_b^T + b_qkv -> SCATTER to Q (pre-scaled), K, VT planes
//   k2: flash attention, 16x16 MFMA, 4 waves x 64 q-rows (kf/vf amortized over
//       4 q-frags), K/VT via global_load_lds (pre-swizzled source), no-max
//       softmax, dbuf, 1 barrier/kt, XCD-local map
//   k0c: w_o -> bf16 into Q-plane (dead after attn)
//   k3: out = vals @ wo_b^T + b_o
// ws: [xb|vals 16.8MB][Q|wo_b 16.8][K 16.8][VT 16.8] = 67.1 MB.

typedef __attribute__((ext_vector_type(4))) float f32x4;
typedef __attribute__((ext_vector_type(8))) short s16x8;
typedef __attribute__((ext_vector_type(2))) unsigned u32x2;
typedef __attribute__((ext_vector_type(4))) unsigned u32x4;

constexpr size_t PART_ELEMS = (size_t)8192 * 1024;  // one bf16 plane

__device__ __forceinline__ unsigned short f2bf(float f) {
  __hip_bfloat16 h = __float2bfloat16(f);
  unsigned short u;
  __builtin_memcpy(&u, &h, 2);
  return u;
}
__device__ __forceinline__ unsigned pack2bf(float a, float b) {
  return (unsigned)f2bf(a) | ((unsigned)f2bf(b) << 16);
}
__device__ __forceinline__ float fexp2(float x) {
#if __has_builtin(__builtin_amdgcn_exp2f)
  return __builtin_amdgcn_exp2f(x);
#else
  float r; asm("v_exp_f32 %0, %1" : "=v"(r) : "v"(x)); return r;
#endif
}
// async global->LDS, 16B per lane. LDS dest is wave-uniform base + lane*16.
__device__ __forceinline__ void gload_lds16(const void* g, void* l) {
  __builtin_amdgcn_global_load_lds(
      (const __attribute__((address_space(1))) unsigned*)g,
      (__attribute__((address_space(3))) unsigned*)l, 16, 0, 0);
}
// XOR-swizzled short-index into a [rows][64]-short tile.
__device__ __forceinline__ int swzs(int row, int col) {
  return row * 64 + (((col >> 3) ^ (row & 7)) << 3) + (col & 7);
}

// ---- k0: fused fp32 -> bf16 convert for x (4096 blocks) + w_qkv (1536) ----
__global__ __launch_bounds__(256) void cvt2_kernel(
    const float* __restrict__ a, unsigned short* __restrict__ oa,
    const float* __restrict__ b, unsigned short* __restrict__ ob) {
  const int bid = blockIdx.x;
  const float* in;
  unsigned short* out;
  size_t i;
  if (bid < 4096) {
    in = a; out = oa; i = ((size_t)bid * 256 + threadIdx.x) * 8;
  } else {
    in = b; out = ob; i = ((size_t)(bid - 4096) * 256 + threadIdx.x) * 8;
  }
  f32x4 v0 = *reinterpret_cast<const f32x4*>(in + i);
  f32x4 v1 = *reinterpret_cast<const f32x4*>(in + i + 4);
  u32x4 pk;
  pk.x = pack2bf(v0.x, v0.y); pk.y = pack2bf(v0.z, v0.w);
  pk.z = pack2bf(v1.x, v1.y); pk.w = pack2bf(v1.z, v1.w);
  *reinterpret_cast<u32x4*>(out + i) = pk;
}

// ---- plain fp32 -> bf16 convert (w_o) ----
__global__ __launch_bounds__(256) void cvt_kernel(const float* __restrict__ in,
                                                  unsigned short* __restrict__ out) {
  const size_t i = ((size_t)blockIdx.x * 256 + threadIdx.x) * 8;
  f32x4 v0 = *reinterpret_cast<const f32x4*>(in + i);
  f32x4 v1 = *reinterpret_cast<const f32x4*>(in + i + 4);
  u32x4 pk;
  pk.x = pack2bf(v0.x, v0.y); pk.y = pack2bf(v0.z, v0.w);
  pk.z = pack2bf(v1.x, v1.y); pk.w = pack2bf(v1.z, v1.w);
  *reinterpret_cast<u32x4*>(out + i) = pk;
}

// C[M,N] = A[M,K](bf16) @ Bw[N,K](bf16)^T + bias.  (unchanged from R14)
template <bool SCATTER>
__global__ __launch_bounds__(256) void gemm_bb(
    const unsigned short* __restrict__ A, const unsigned short* __restrict__ Bw,
    const float* __restrict__ bias, void* __restrict__ Cptr,
    int M, int N, int K) {
  __shared__ short lds_a[128 * 64];
  __shared__ short lds_b[128 * 64];
  const int t = threadIdx.x;
  const int l = t & 63;
  const int w = t >> 6;
  const int id = blockIdx.x;
  const int xcd = id & 7;
  const int rr = id >> 3;
  const int bm = (xcd * 8 + (rr & 7)) * 128;
  const int bn = (rr >> 3) * 128;
  const int wr = (w >> 1) * 64;
  const int wc = (w & 1) * 64;
  const int lr = l & 15;
  const int lkh = l >> 4;

  f32x4 acc[4][4] = {};

  const int c8 = l >> 3;
  const int gcol = ((l & 7) ^ c8) * 8;

  for (int k0 = 0; k0 < K; k0 += 64) {
    const unsigned short* as = &A[(size_t)(bm + w * 32 + c8) * K + k0 + gcol];
    const unsigned short* bs = &Bw[(size_t)(bn + w * 32 + c8) * K + k0 + gcol];
#pragma unroll
    for (int c = 0; c < 4; ++c) {
      gload_lds16(as + (size_t)(c * 8) * K, &lds_a[(w * 32 + c * 8) * 64]);
      gload_lds16(bs + (size_t)(c * 8) * K, &lds_b[(w * 32 + c * 8) * 64]);
    }
    __syncthreads();

#pragma unroll
    for (int ki = 0; ki < 2; ++ki) {
      s16x8 af[4], bfr[4];
#pragma unroll
      for (int mt = 0; mt < 4; ++mt) {
        const int row = wr + mt * 16 + lr;
        af[mt] = *reinterpret_cast<const s16x8*>(
            &lds_a[row * 64 + ((((ki << 2) + lkh) ^ (lr & 7)) << 3)]);
      }
#pragma unroll
      for (int nt = 0; nt < 4; ++nt) {
        const int row = wc + nt * 16 + lr;
        bfr[nt] = *reinterpret_cast<const s16x8*>(
            &lds_b[row * 64 + ((((ki << 2) + lkh) ^ (lr & 7)) << 3)]);
      }
#pragma unroll
      for (int mt = 0; mt < 4; ++mt)
#pragma unroll
        for (int nt = 0; nt < 4; ++nt)
          acc[mt][nt] = __builtin_amdgcn_mfma_f32_16x16x32_bf16(af[mt], bfr[nt], acc[mt][nt], 0, 0, 0);
    }
    __syncthreads();
  }

  if (SCATTER) {
    unsigned short* W = (unsigned short*)Cptr;
    const int s0 = (bm & 2047) + wr + (l >> 4) * 4;
    const int batch = bm >> 11;
#pragma unroll
    for (int nt = 0; nt < 4; ++nt) {
      const int col = bn + wc + nt * 16 + lr;
      const int h = col / 192;
      const int rem = col - h * 192;
      const int part = rem >> 6;          // 0=Q 1=K 2=V
      const int d = rem & 63;
      const size_t bh = (size_t)batch * 16 + h;
      const float bv = bias[col];
      unsigned short* base;
      int stride;
      float scale;
      if (part == 2) {
        base = W + 2 * PART_ELEMS + (bh * 64 + d) * 2048;   // VT[bh][d][s]
        stride = 1;
        scale = 1.0f;
      } else {
        base = W + (size_t)part * PART_ELEMS + bh * 2048 * 64 + d;  // Q/K[bh][s][d]
        stride = 64;
        scale = (part == 0) ? 0.1803368801f : 1.0f;         // 0.125*log2e on Q
      }
      unsigned short* p = base + (size_t)s0 * stride;
#pragma unroll
      for (int mt = 0; mt < 4; ++mt) {
        unsigned short* pm = p + mt * 16 * stride;
#pragma unroll
        for (int r = 0; r < 4; ++r)
          pm[r * stride] = f2bf((acc[mt][nt][r] + bv) * scale);
      }
    }
  } else {
    float* C = (float*)Cptr;
#pragma unroll
    for (int mt = 0; mt < 4; ++mt) {
#pragma unroll
      for (int nt = 0; nt < 4; ++nt) {
        const int col = bn + wc + nt * 16 + lr;
        const float bv = bias[col];
#pragma unroll
        for (int r = 0; r < 4; ++r) {
          const int row = bm + wr + mt * 16 + (l >> 4) * 4 + r;
          C[(size_t)row * N + col] = acc[mt][nt][r] + bv;
        }
      }
    }
  }
}

// Flash attention over planes Q[bh][s][64] (pre-scaled), K[bh][s][64], VT[bh][d][s].
// 4 waves/block, 256 q-rows (64/wave, 4 q-frags of 16); KV tile 64, double-
// buffered via global_load_lds (linear dest + pre-swizzled source; swzs reads),
// ONE barrier per kt. kf/vf fragment loads amortized over 4 q-frags (the LDS
// pipe was the binding resource). Swapped QK^T, NO-MAX softmax, lane-local l.
// LDS 64 KB -> 2 blocks/CU (8 waves). XCD-local flat-grid decode.
__global__ __launch_bounds__(256, 2) void attn_kernel(
    const unsigned short* __restrict__ ws, unsigned short* __restrict__ vals) {
  __shared__ short k_lds[2][64 * 64];
  __shared__ short vt_lds[2][64 * 64];
  __shared__ short p_lds[256 * 64];
  const int t = threadIdx.x;
  const int l = t & 63;
  const int w = t >> 6;            // 0..3
  const int lr = l & 15;
  const int lkh = l >> 4;
  const int f = blockIdx.x;        // 0..511
  const int xcd = f & 7;
  const int j = f >> 3;            // 0..63
  const int bh = xcd * 8 + (j & 7);
  const int qt = j >> 3;           // 0..7
  const int b = bh >> 4;
  const int h = bh & 15;
  const unsigned short* Qh  = ws + (size_t)bh * (2048 * 64);
  const unsigned short* Kh  = ws + PART_ELEMS + (size_t)bh * (2048 * 64);
  const unsigned short* VTh = ws + 2 * PART_ELEMS + (size_t)bh * (64 * 2048);

  // staging: wave w owns tile rows w*16..w*16+15, in two 8-row gload chunks;
  // lane covers row base + (l>>3), LDS 16B-unit (l&7), global unit pre-swizzled.
  const int sr8 = l >> 3;                  // 0..7  (== row&7 for both chunks)
  const int gcu = (l & 7) ^ sr8;           // pre-swizzled source unit
  const unsigned short* Ks = Kh + (size_t)(w * 16 + sr8) * 64 + gcu * 8;
  const unsigned short* Vs = VTh + (size_t)(w * 16 + sr8) * 2048 + gcu * 8;

  // ---- Q fragments (already scaled by 0.125*log2e): 4 q-frags of 16 rows ----
  s16x8 qf[4][2];
#pragma unroll
  for (int qh = 0; qh < 4; ++qh) {
    const unsigned short* qb =
        Qh + ((size_t)qt * 256 + w * 64 + qh * 16 + lr) * 64 + lkh * 8;
    qf[qh][0] = *reinterpret_cast<const s16x8*>(qb);
    qf[qh][1] = *reinterpret_cast<const s16x8*>(qb + 32);
  }

  // ---- stage K/VT tile 0 into buffer 0 ----
  gload_lds16(Ks, &k_lds[0][(w * 16) * 64]);
  gload_lds16(Ks + 8 * 64, &k_lds[0][(w * 16 + 8) * 64]);
  gload_lds16(Vs, &vt_lds[0][(w * 16) * 64]);
  gload_lds16(Vs + 8 * 2048, &vt_lds[0][(w * 16 + 8) * 64]);
  __syncthreads();

  f32x4 o_acc[4][4] = {};
  float l_s[4] = {0.f, 0.f, 0.f, 0.f};   // lane-local partials (deferred reduce)

  for (int kt = 0; kt < 32; ++kt) {
    const int cur = kt & 1;
    const int nxt = cur ^ 1;

    // ---- async prefetch next tile into the other buffer ----
    if (kt + 1 < 32) {
      const unsigned short* kp = Ks + (size_t)(kt + 1) * 4096;
      const unsigned short* vp = Vs + (size_t)(kt + 1) * 64;
      gload_lds16(kp, &k_lds[nxt][(w * 16) * 64]);
      gload_lds16(kp + 8 * 64, &k_lds[nxt][(w * 16 + 8) * 64]);
      gload_lds16(vp, &vt_lds[nxt][(w * 16) * 64]);
      gload_lds16(vp + 8 * 2048, &vt_lds[nxt][(w * 16 + 8) * 64]);
    }

    // ---- kf loaded ONCE, reused across 4 q-frags ----
    s16x8 kf[4][2];
#pragma unroll
    for (int nt = 0; nt < 4; ++nt) {
      kf[nt][0] = *reinterpret_cast<const s16x8*>(&k_lds[cur][swzs(nt * 16 + lr, lkh * 8)]);
      kf[nt][1] = *reinterpret_cast<const s16x8*>(&k_lds[cur][swzs(nt * 16 + lr, 32 + lkh * 8)]);
    }
#pragma unroll
    for (int qh = 0; qh < 4; ++qh) {
      // S^T = K Q^T for this q-frag
      f32x4 s_acc[4] = {};
      __builtin_amdgcn_s_setprio(1);
#pragma unroll
      for (int nt = 0; nt < 4; ++nt) {
        s_acc[nt] = __builtin_amdgcn_mfma_f32_16x16x32_bf16(kf[nt][0], qf[qh][0], s_acc[nt], 0, 0, 0);
        s_acc[nt] = __builtin_amdgcn_mfma_f32_16x16x32_bf16(kf[nt][1], qf[qh][1], s_acc[nt], 0, 0, 0);
      }
      __builtin_amdgcn_s_setprio(0);
      // NO-MAX softmax: P = exp2(s); lane-local l partial
      float rs = 0.f;
#pragma unroll
      for (int nt = 0; nt < 4; ++nt) {
        float p0 = fexp2(s_acc[nt][0]);
        float p1 = fexp2(s_acc[nt][1]);
        float p2 = fexp2(s_acc[nt][2]);
        float p3 = fexp2(s_acc[nt][3]);
        rs += (p0 + p1) + (p2 + p3);
        u32x2 pk;
        pk.x = pack2bf(p0, p1);
        pk.y = pack2bf(p2, p3);
        *reinterpret_cast<u32x2*>(
            &p_lds[swzs(w * 64 + qh * 16 + lr, nt * 16 + 4 * lkh)]) = pk;
      }
      l_s[qh] += rs;
    }

    // ---- vf loaded ONCE, reused across 4 q-frags ----
    s16x8 vf[4][2];
#pragma unroll
    for (int nt = 0; nt < 4; ++nt) {
      vf[nt][0] = *reinterpret_cast<const s16x8*>(&vt_lds[cur][swzs(nt * 16 + lr, lkh * 8)]);
      vf[nt][1] = *reinterpret_cast<const s16x8*>(&vt_lds[cur][swzs(nt * 16 + lr, 32 + lkh * 8)]);
    }
#pragma unroll
    for (int qh = 0; qh < 4; ++qh) {
      s16x8 pf0 = *reinterpret_cast<const s16x8*>(
          &p_lds[swzs(w * 64 + qh * 16 + lr, lkh * 8)]);
      s16x8 pf1 = *reinterpret_cast<const s16x8*>(
          &p_lds[swzs(w * 64 + qh * 16 + lr, 32 + lkh * 8)]);
      __builtin_amdgcn_s_setprio(1);
#pragma unroll
      for (int nt = 0; nt < 4; ++nt) {
        o_acc[qh][nt] = __builtin_amdgcn_mfma_f32_16x16x32_bf16(pf0, vf[nt][0], o_acc[qh][nt], 0, 0, 0);
        o_acc[qh][nt] = __builtin_amdgcn_mfma_f32_16x16x32_bf16(pf1, vf[nt][1], o_acc[qh][nt], 0, 0, 0);
      }
      __builtin_amdgcn_s_setprio(0);
    }
    __syncthreads();  // reads of cur done; prefetch into nxt drained (vmcnt)
  }

  // ---- deferred l reduction, then epilogue ----
#pragma unroll
  for (int qh = 0; qh < 4; ++qh) {
    l_s[qh] += __shfl_xor(l_s[qh], 16);
    l_s[qh] += __shfl_xor(l_s[qh], 32);
  }
#pragma unroll
  for (int qh = 0; qh < 4; ++qh) {
#pragma unroll
    for (int r = 0; r < 4; ++r) {
      const float lv = __shfl(l_s[qh], 4 * lkh + r);
      const float inv = 1.0f / lv;
      const size_t row =
          (size_t)b * 2048 + qt * 256 + w * 64 + qh * 16 + lkh * 4 + r;
#pragma unroll
      for (int nt = 0; nt < 4; ++nt) {
        vals[row * 1024 + h * 64 + nt * 16 + lr] = f2bf(o_acc[qh][nt][r] * inv);
      }
    }
  }
}

extern "C" void kernel_launch(void* const* d_in, const int* in_sizes, int n_in,
                              void* d_out, int out_size, void* d_ws, size_t ws_size,
                              hipStream_t stream) {
  const float* x     = (const float*)d_in[0];   // [4,2048,1024]
  const float* w_qkv = (const float*)d_in[1];   // [3072,1024]
  const float* b_qkv = (const float*)d_in[2];   // [3072]
  const float* w_o   = (const float*)d_in[3];   // [1024,1024]
  const float* b_o   = (const float*)d_in[4];   // [1024]
  float* out = (float*)d_out;                   // [4,2048,1024] fp32

  unsigned short* xb     = (unsigned short*)d_ws;   // x bf16; later: vals (aliased)
  unsigned short* planes = xb + PART_ELEMS;         // Q | K | VT planes
  unsigned short* wqkv_b = (unsigned short*)d_out;  // d_out scratch (read only by gemm1)
  unsigned short* wo_b   = planes;                  // Q-plane, dead after attn

  cvt2_kernel<<<5632, 256, 0, stream>>>(x, xb, w_qkv, wqkv_b);      // x + w_qkv -> bf16
  gemm_bb<true><<<1536, 256, 0, stream>>>(
      xb, wqkv_b, b_qkv, planes, 8192, 3072, 1024);                 // qkv + scatter
  attn_kernel<<<512, 256, 0, stream>>>(planes, xb);                 // vals -> xb
  cvt_kernel<<<512, 256, 0, stream>>>(w_o, wo_b);                   // w_o -> bf16 (Q-plane)
  gemm_bb<false><<<512, 256, 0, stream>>>(
      xb, wo_b, b_o, out, 8192, 1024, 1024);                        // out proj
}

// Round 18
// 197.282 us; speedup vs baseline: 1.0474x; 1.0271x over previous
//
#include <hip/hip_runtime.h>
#include <hip/hip_bf16.h>

// MHA fused pipeline: B=4, S=2048, D=1024, H=16, HD=64.
//   k0: fused cvt: x -> xb bf16, w_qkv -> wqkv_b bf16 (d_out scratch)
//   k1: qkv = xb @ wqkv_b^T + b_qkv -> SCATTER to Q (pre-scaled), K, VT planes
//   k2: flash attention (R14 structure: 8 waves, 32 q/wave, dbuf, 1 barrier/kt,
//       no-max softmax) with K/VT staged via global_load_lds (linear dest +
//       pre-swizzled source unit; swzs reads) instead of reg-staging
//   k0c: w_o -> bf16 into Q-plane (dead after attn)
//   k3: out = vals @ wo_b^T + b_o
// ws: [xb|vals 16.8MB][Q|wo_b 16.8][K 16.8][VT 16.8] = 67.1 MB.

typedef __attribute__((ext_vector_type(4))) float f32x4;
typedef __attribute__((ext_vector_type(8))) short s16x8;
typedef __attribute__((ext_vector_type(2))) unsigned u32x2;
typedef __attribute__((ext_vector_type(4))) unsigned u32x4;

constexpr size_t PART_ELEMS = (size_t)8192 * 1024;  // one bf16 plane

__device__ __forceinline__ unsigned short f2bf(float f) {
  __hip_bfloat16 h = __float2bfloat16(f);
  unsigned short u;
  __builtin_memcpy(&u, &h, 2);
  return u;
}
__device__ __forceinline__ unsigned pack2bf(float a, float b) {
  return (unsigned)f2bf(a) | ((unsigned)f2bf(b) << 16);
}
__device__ __forceinline__ float fexp2(float x) {
#if __has_builtin(__builtin_amdgcn_exp2f)
  return __builtin_amdgcn_exp2f(x);
#else
  float r; asm("v_exp_f32 %0, %1" : "=v"(r) : "v"(x)); return r;
#endif
}
// async global->LDS, 16B per lane. LDS dest is wave-uniform base + lane*16.
__device__ __forceinline__ void gload_lds16(const void* g, void* l) {
  __builtin_amdgcn_global_load_lds(
      (const __attribute__((address_space(1))) unsigned*)g,
      (__attribute__((address_space(3))) unsigned*)l, 16, 0, 0);
}
// XOR-swizzled short-index into a [rows][64]-short tile.
__device__ __forceinline__ int swzs(int row, int col) {
  return row * 64 + (((col >> 3) ^ (row & 7)) << 3) + (col & 7);
}

// ---- k0: fused fp32 -> bf16 convert for x (4096 blocks) + w_qkv (1536) ----
__global__ __launch_bounds__(256) void cvt2_kernel(
    const float* __restrict__ a, unsigned short* __restrict__ oa,
    const float* __restrict__ b, unsigned short* __restrict__ ob) {
  const int bid = blockIdx.x;
  const float* in;
  unsigned short* out;
  size_t i;
  if (bid < 4096) {
    in = a; out = oa; i = ((size_t)bid * 256 + threadIdx.x) * 8;
  } else {
    in = b; out = ob; i = ((size_t)(bid - 4096) * 256 + threadIdx.x) * 8;
  }
  f32x4 v0 = *reinterpret_cast<const f32x4*>(in + i);
  f32x4 v1 = *reinterpret_cast<const f32x4*>(in + i + 4);
  u32x4 pk;
  pk.x = pack2bf(v0.x, v0.y); pk.y = pack2bf(v0.z, v0.w);
  pk.z = pack2bf(v1.x, v1.y); pk.w = pack2bf(v1.z, v1.w);
  *reinterpret_cast<u32x4*>(out + i) = pk;
}

// ---- plain fp32 -> bf16 convert (w_o) ----
__global__ __launch_bounds__(256) void cvt_kernel(const float* __restrict__ in,
                                                  unsigned short* __restrict__ out) {
  const size_t i = ((size_t)blockIdx.x * 256 + threadIdx.x) * 8;
  f32x4 v0 = *reinterpret_cast<const f32x4*>(in + i);
  f32x4 v1 = *reinterpret_cast<const f32x4*>(in + i + 4);
  u32x4 pk;
  pk.x = pack2bf(v0.x, v0.y); pk.y = pack2bf(v0.z, v0.w);
  pk.z = pack2bf(v1.x, v1.y); pk.w = pack2bf(v1.z, v1.w);
  *reinterpret_cast<u32x4*>(out + i) = pk;
}

// C[M,N] = A[M,K](bf16) @ Bw[N,K](bf16)^T + bias.  (unchanged from R14)
// BK=64; both operands via global_load_lds into linear [128][64] LDS, 16B-unit
// column pre-swizzled on the GLOBAL side; same XOR on fragment reads.
// Flat grid, XCD bm-chunked: XCD c owns bm tiles [c*8, c*8+8) x all bn.
template <bool SCATTER>
__global__ __launch_bounds__(256) void gemm_bb(
    const unsigned short* __restrict__ A, const unsigned short* __restrict__ Bw,
    const float* __restrict__ bias, void* __restrict__ Cptr,
    int M, int N, int K) {
  __shared__ short lds_a[128 * 64];
  __shared__ short lds_b[128 * 64];
  const int t = threadIdx.x;
  const int l = t & 63;
  const int w = t >> 6;
  const int id = blockIdx.x;
  const int xcd = id & 7;
  const int rr = id >> 3;
  const int bm = (xcd * 8 + (rr & 7)) * 128;
  const int bn = (rr >> 3) * 128;
  const int wr = (w >> 1) * 64;
  const int wc = (w & 1) * 64;
  const int lr = l & 15;
  const int lkh = l >> 4;

  f32x4 acc[4][4] = {};

  const int c8 = l >> 3;
  const int gcol = ((l & 7) ^ c8) * 8;

  for (int k0 = 0; k0 < K; k0 += 64) {
    const unsigned short* as = &A[(size_t)(bm + w * 32 + c8) * K + k0 + gcol];
    const unsigned short* bs = &Bw[(size_t)(bn + w * 32 + c8) * K + k0 + gcol];
#pragma unroll
    for (int c = 0; c < 4; ++c) {
      gload_lds16(as + (size_t)(c * 8) * K, &lds_a[(w * 32 + c * 8) * 64]);
      gload_lds16(bs + (size_t)(c * 8) * K, &lds_b[(w * 32 + c * 8) * 64]);
    }
    __syncthreads();

#pragma unroll
    for (int ki = 0; ki < 2; ++ki) {
      s16x8 af[4], bfr[4];
#pragma unroll
      for (int mt = 0; mt < 4; ++mt) {
        const int row = wr + mt * 16 + lr;
        af[mt] = *reinterpret_cast<const s16x8*>(
            &lds_a[row * 64 + ((((ki << 2) + lkh) ^ (lr & 7)) << 3)]);
      }
#pragma unroll
      for (int nt = 0; nt < 4; ++nt) {
        const int row = wc + nt * 16 + lr;
        bfr[nt] = *reinterpret_cast<const s16x8*>(
            &lds_b[row * 64 + ((((ki << 2) + lkh) ^ (lr & 7)) << 3)]);
      }
#pragma unroll
      for (int mt = 0; mt < 4; ++mt)
#pragma unroll
        for (int nt = 0; nt < 4; ++nt)
          acc[mt][nt] = __builtin_amdgcn_mfma_f32_16x16x32_bf16(af[mt], bfr[nt], acc[mt][nt], 0, 0, 0);
    }
    __syncthreads();
  }

  if (SCATTER) {
    unsigned short* W = (unsigned short*)Cptr;
    const int s0 = (bm & 2047) + wr + (l >> 4) * 4;
    const int batch = bm >> 11;
#pragma unroll
    for (int nt = 0; nt < 4; ++nt) {
      const int col = bn + wc + nt * 16 + lr;
      const int h = col / 192;
      const int rem = col - h * 192;
      const int part = rem >> 6;          // 0=Q 1=K 2=V
      const int d = rem & 63;
      const size_t bh = (size_t)batch * 16 + h;
      const float bv = bias[col];
      unsigned short* base;
      int stride;
      float scale;
      if (part == 2) {
        base = W + 2 * PART_ELEMS + (bh * 64 + d) * 2048;   // VT[bh][d][s]
        stride = 1;
        scale = 1.0f;
      } else {
        base = W + (size_t)part * PART_ELEMS + bh * 2048 * 64 + d;  // Q/K[bh][s][d]
        stride = 64;
        scale = (part == 0) ? 0.1803368801f : 1.0f;         // 0.125*log2e on Q
      }
      unsigned short* p = base + (size_t)s0 * stride;
#pragma unroll
      for (int mt = 0; mt < 4; ++mt) {
        unsigned short* pm = p + mt * 16 * stride;
#pragma unroll
        for (int r = 0; r < 4; ++r)
          pm[r * stride] = f2bf((acc[mt][nt][r] + bv) * scale);
      }
    }
  } else {
    float* C = (float*)Cptr;
#pragma unroll
    for (int mt = 0; mt < 4; ++mt) {
#pragma unroll
      for (int nt = 0; nt < 4; ++nt) {
        const int col = bn + wc + nt * 16 + lr;
        const float bv = bias[col];
#pragma unroll
        for (int r = 0; r < 4; ++r) {
          const int row = bm + wr + mt * 16 + (l >> 4) * 4 + r;
          C[(size_t)row * N + col] = acc[mt][nt][r] + bv;
        }
      }
    }
  }
}

// Flash attention over planes Q[bh][s][64] (pre-scaled), K[bh][s][64], VT[bh][d][s].
// 8 waves/block, 256 q-rows (32/wave); KV tile 64, double-buffered, ONE barrier
// per kt. K/VT staged via global_load_lds: wave w writes its 8-row chunk
// (1 KB) linearly from a pre-swizzled global source; reads use swzs (the same
// involution). XCD-local flat-grid decode. Swapped QK^T, NO-MAX softmax
// (shift-invariant; |s| << 60), lane-local l partials. LDS 64 KB.
__global__ __launch_bounds__(512, 4) void attn_kernel(
    const unsigned short* __restrict__ ws, unsigned short* __restrict__ vals) {
  __shared__ short k_lds[2][64 * 64];
  __shared__ short vt_lds[2][64 * 64];
  __shared__ short p_lds[256 * 64];
  const int t = threadIdx.x;
  const int l = t & 63;
  const int w = t >> 6;            // 0..7
  const int lr = l & 15;
  const int lkh = l >> 4;
  const int f = blockIdx.x;        // 0..511
  const int xcd = f & 7;
  const int j = f >> 3;            // 0..63
  const int bh = xcd * 8 + (j & 7);
  const int qt = j >> 3;           // 0..7
  const int b = bh >> 4;
  const int h = bh & 15;
  const unsigned short* Qh  = ws + (size_t)bh * (2048 * 64);
  const unsigned short* Kh  = ws + PART_ELEMS + (size_t)bh * (2048 * 64);
  const unsigned short* VTh = ws + 2 * PART_ELEMS + (size_t)bh * (64 * 2048);

  // staging: wave w owns tile rows w*8..w*8+7 (1 KB chunk). Lane covers row
  // w*8 + (l>>3); LDS 16B-unit is linear (l&7), global unit pre-swizzled.
  const int sr8 = l >> 3;                  // row-in-chunk == row&7
  const int gcu = (l & 7) ^ sr8;           // pre-swizzled source unit
  const unsigned short* Ks = Kh + (size_t)(w * 8 + sr8) * 64 + gcu * 8;
  const unsigned short* Vs = VTh + (size_t)(w * 8 + sr8) * 2048 + gcu * 8;

  s16x8 qf[2][2];
  {
    const unsigned short* qb = Qh + ((size_t)qt * 256 + w * 32 + lr) * 64 + lkh * 8;
    qf[0][0] = *reinterpret_cast<const s16x8*>(qb);
    qf[0][1] = *reinterpret_cast<const s16x8*>(qb + 32);
    qf[1][0] = *reinterpret_cast<const s16x8*>(qb + 16 * 64);
    qf[1][1] = *reinterpret_cast<const s16x8*>(qb + 16 * 64 + 32);
  }
  // ---- stage K/VT tile 0 into buffer 0 ----
  gload_lds16(Ks, &k_lds[0][(w * 8) * 64]);
  gload_lds16(Vs, &vt_lds[0][(w * 8) * 64]);
  __syncthreads();

  f32x4 o_acc[2][4] = {};
  float l_s[2] = {0.f, 0.f};       // lane-local partial (deferred reduction)

  for (int kt = 0; kt < 32; ++kt) {
    const int cur = kt & 1;
    const int nxt = cur ^ 1;

    // ---- issue async prefetch of next tile into the other buffer ----
    if (kt + 1 < 32) {
      gload_lds16(Ks + (size_t)(kt + 1) * 4096, &k_lds[nxt][(w * 8) * 64]);
      gload_lds16(Vs + (size_t)(kt + 1) * 64, &vt_lds[nxt][(w * 8) * 64]);
    }

    // ---- S^T = K Q^T (swapped); kf shared across both q-halves ----
    f32x4 s_acc[2][4] = {};
    {
      s16x8 kf[4][2];
#pragma unroll
      for (int nt = 0; nt < 4; ++nt) {
        kf[nt][0] = *reinterpret_cast<const s16x8*>(&k_lds[cur][swzs(nt * 16 + lr, lkh * 8)]);
        kf[nt][1] = *reinterpret_cast<const s16x8*>(&k_lds[cur][swzs(nt * 16 + lr, 32 + lkh * 8)]);
      }
      __builtin_amdgcn_s_setprio(1);
#pragma unroll
      for (int qh = 0; qh < 2; ++qh)
#pragma unroll
        for (int nt = 0; nt < 4; ++nt) {
          s_acc[qh][nt] = __builtin_amdgcn_mfma_f32_16x16x32_bf16(kf[nt][0], qf[qh][0], s_acc[qh][nt], 0, 0, 0);
          s_acc[qh][nt] = __builtin_amdgcn_mfma_f32_16x16x32_bf16(kf[nt][1], qf[qh][1], s_acc[qh][nt], 0, 0, 0);
        }
      __builtin_amdgcn_s_setprio(0);
    }

    // ---- NO-MAX softmax: P = exp2(s) straight; lane-local l partials ----
#pragma unroll
    for (int qh = 0; qh < 2; ++qh) {
      float rs = 0.f;
#pragma unroll
      for (int nt = 0; nt < 4; ++nt) {
        float p0 = fexp2(s_acc[qh][nt][0]);
        float p1 = fexp2(s_acc[qh][nt][1]);
        float p2 = fexp2(s_acc[qh][nt][2]);
        float p3 = fexp2(s_acc[qh][nt][3]);
        rs += (p0 + p1) + (p2 + p3);
        u32x2 pk;
        pk.x = pack2bf(p0, p1);
        pk.y = pack2bf(p2, p3);
        *reinterpret_cast<u32x2*>(&p_lds[swzs(w * 32 + qh * 16 + lr, nt * 16 + 4 * lkh)]) = pk;
      }
      l_s[qh] += rs;
    }

    // ---- O += P @ V; vf shared across both q-halves ----
    {
      s16x8 vf[4][2];
#pragma unroll
      for (int nt = 0; nt < 4; ++nt) {
        vf[nt][0] = *reinterpret_cast<const s16x8*>(&vt_lds[cur][swzs(nt * 16 + lr, lkh * 8)]);
        vf[nt][1] = *reinterpret_cast<const s16x8*>(&vt_lds[cur][swzs(nt * 16 + lr, 32 + lkh * 8)]);
      }
      __builtin_amdgcn_s_setprio(1);
#pragma unroll
      for (int qh = 0; qh < 2; ++qh) {
        s16x8 pf0 = *reinterpret_cast<const s16x8*>(&p_lds[swzs(w * 32 + qh * 16 + lr, lkh * 8)]);
        s16x8 pf1 = *reinterpret_cast<const s16x8*>(&p_lds[swzs(w * 32 + qh * 16 + lr, 32 + lkh * 8)]);
#pragma unroll
        for (int nt = 0; nt < 4; ++nt) {
          o_acc[qh][nt] = __builtin_amdgcn_mfma_f32_16x16x32_bf16(pf0, vf[nt][0], o_acc[qh][nt], 0, 0, 0);
          o_acc[qh][nt] = __builtin_amdgcn_mfma_f32_16x16x32_bf16(pf1, vf[nt][1], o_acc[qh][nt], 0, 0, 0);
        }
      }
      __builtin_amdgcn_s_setprio(0);
    }

    // ONE barrier per kt: drains vmcnt (prefetch landed) + orders buffer reuse
    __syncthreads();
  }

  // ---- deferred l reduction, then epilogue ----
#pragma unroll
  for (int qh = 0; qh < 2; ++qh) {
    l_s[qh] += __shfl_xor(l_s[qh], 16);
    l_s[qh] += __shfl_xor(l_s[qh], 32);
  }
#pragma unroll
  for (int qh = 0; qh < 2; ++qh) {
#pragma unroll
    for (int r = 0; r < 4; ++r) {
      const float lv = __shfl(l_s[qh], 4 * lkh + r);
      const float inv = 1.0f / lv;
      const size_t row = (size_t)b * 2048 + qt * 256 + w * 32 + qh * 16 + lkh * 4 + r;
#pragma unroll
      for (int nt = 0; nt < 4; ++nt) {
        vals[row * 1024 + h * 64 + nt * 16 + lr] = f2bf(o_acc[qh][nt][r] * inv);
      }
    }
  }
}

extern "C" void kernel_launch(void* const* d_in, const int* in_sizes, int n_in,
                              void* d_out, int out_size, void* d_ws, size_t ws_size,
                              hipStream_t stream) {
  const float* x     = (const float*)d_in[0];   // [4,2048,1024]
  const float* w_qkv = (const float*)d_in[1];   // [3072,1024]
  const float* b_qkv = (const float*)d_in[2];   // [3072]
  const float* w_o   = (const float*)d_in[3];   // [1024,1024]
  const float* b_o   = (const float*)d_in[4];   // [1024]
  float* out = (float*)d_out;                   // [4,2048,1024] fp32

  unsigned short* xb     = (unsigned short*)d_ws;   // x bf16; later: vals (aliased)
  unsigned short* planes = xb + PART_ELEMS;         // Q | K | VT planes
  unsigned short* wqkv_b = (unsigned short*)d_out;  // d_out scratch (read only by gemm1)
  unsigned short* wo_b   = planes;                  // Q-plane, dead after attn

  cvt2_kernel<<<5632, 256, 0, stream>>>(x, xb, w_qkv, wqkv_b);      // x + w_qkv -> bf16
  gemm_bb<true><<<1536, 256, 0, stream>>>(
      xb, wqkv_b, b_qkv, planes, 8192, 3072, 1024);                 // qkv + scatter
  attn_kernel<<<512, 512, 0, stream>>>(planes, xb);                 // vals -> xb
  cvt_kernel<<<512, 256, 0, stream>>>(w_o, wo_b);                   // w_o -> bf16 (Q-plane)
  gemm_bb<false><<<512, 256, 0, stream>>>(
      xb, wo_b, b_o, out, 8192, 1024, 1024);                        // out proj
}

// Round 19
// 193.788 us; speedup vs baseline: 1.0662x; 1.0180x over previous
//
#include <hip/hip_runtime.h>
#include <hip/hip_bf16.h>

// MHA fused pipeline: B=4, S=2048, D=1024, H=16, HD=64.  (R14 configuration —
// best measured: 193.6 us. R15-R18 variants all regressed; this is the
// verified local optimum of this structure.)
//   k0: fused cvt: x -> xb bf16, w_qkv -> wqkv_b bf16 (d_out scratch)
//   k1: qkv = xb @ wqkv_b^T + b_qkv -> SCATTER to Q (pre-scaled), K, VT planes
//   k2: flash attention: 8 waves x 32 q-rows, reg-staged dbuf K/VT,
//       1 barrier/kt, swapped QK^T, NO-MAX softmax, deferred l, XCD-local map
//   k0c: w_o -> bf16 into Q-plane (dead after attn)
//   k3: out = vals @ wo_b^T + b_o
// GEMMs: BK=64, global_load_lds with PRE-SWIZZLED SOURCE + XOR-swizzled reads,
// hoisted scatter decode, XCD bm-chunked grid.
// ws: [xb|vals 16.8MB][Q|wo_b 16.8][K 16.8][VT 16.8] = 67.1 MB.

typedef __attribute__((ext_vector_type(4))) float f32x4;
typedef __attribute__((ext_vector_type(8))) short s16x8;
typedef __attribute__((ext_vector_type(2))) unsigned u32x2;
typedef __attribute__((ext_vector_type(4))) unsigned u32x4;

constexpr size_t PART_ELEMS = (size_t)8192 * 1024;  // one bf16 plane

__device__ __forceinline__ unsigned short f2bf(float f) {
  __hip_bfloat16 h = __float2bfloat16(f);
  unsigned short u;
  __builtin_memcpy(&u, &h, 2);
  return u;
}
__device__ __forceinline__ unsigned pack2bf(float a, float b) {
  return (unsigned)f2bf(a) | ((unsigned)f2bf(b) << 16);
}
__device__ __forceinline__ float fexp2(float x) {
#if __has_builtin(__builtin_amdgcn_exp2f)
  return __builtin_amdgcn_exp2f(x);
#else
  float r; asm("v_exp_f32 %0, %1" : "=v"(r) : "v"(x)); return r;
#endif
}
// async global->LDS, 16B per lane. LDS dest is wave-uniform base + lane*16.
__device__ __forceinline__ void gload_lds16(const void* g, void* l) {
  __builtin_amdgcn_global_load_lds(
      (const __attribute__((address_space(1))) unsigned*)g,
      (__attribute__((address_space(3))) unsigned*)l, 16, 0, 0);
}
// XOR-swizzled short-index into a [rows][64]-short tile (attn LDS).
__device__ __forceinline__ int swzs(int row, int col) {
  return row * 64 + (((col >> 3) ^ (row & 7)) << 3) + (col & 7);
}

// ---- k0: fused fp32 -> bf16 convert for x (4096 blocks) + w_qkv (1536) ----
__global__ __launch_bounds__(256) void cvt2_kernel(
    const float* __restrict__ a, unsigned short* __restrict__ oa,
    const float* __restrict__ b, unsigned short* __restrict__ ob) {
  const int bid = blockIdx.x;
  const float* in;
  unsigned short* out;
  size_t i;
  if (bid < 4096) {
    in = a; out = oa; i = ((size_t)bid * 256 + threadIdx.x) * 8;
  } else {
    in = b; out = ob; i = ((size_t)(bid - 4096) * 256 + threadIdx.x) * 8;
  }
  f32x4 v0 = *reinterpret_cast<const f32x4*>(in + i);
  f32x4 v1 = *reinterpret_cast<const f32x4*>(in + i + 4);
  u32x4 pk;
  pk.x = pack2bf(v0.x, v0.y); pk.y = pack2bf(v0.z, v0.w);
  pk.z = pack2bf(v1.x, v1.y); pk.w = pack2bf(v1.z, v1.w);
  *reinterpret_cast<u32x4*>(out + i) = pk;
}

// ---- plain fp32 -> bf16 convert (w_o) ----
__global__ __launch_bounds__(256) void cvt_kernel(const float* __restrict__ in,
                                                  unsigned short* __restrict__ out) {
  const size_t i = ((size_t)blockIdx.x * 256 + threadIdx.x) * 8;
  f32x4 v0 = *reinterpret_cast<const f32x4*>(in + i);
  f32x4 v1 = *reinterpret_cast<const f32x4*>(in + i + 4);
  u32x4 pk;
  pk.x = pack2bf(v0.x, v0.y); pk.y = pack2bf(v0.z, v0.w);
  pk.z = pack2bf(v1.x, v1.y); pk.w = pack2bf(v1.z, v1.w);
  *reinterpret_cast<u32x4*>(out + i) = pk;
}

// C[M,N] = A[M,K](bf16) @ Bw[N,K](bf16)^T + bias.
// BK=64; both operands via global_load_lds into linear [128][64] LDS, with the
// 16B-unit column pre-swizzled on the GLOBAL side (u_src = u ^ (row&7)) and the
// same XOR applied on fragment reads -> conflict-free ds_read_b128.
// Flat grid, XCD bm-chunked: XCD c owns bm tiles [c*8, c*8+8) x all bn.
template <bool SCATTER>
__global__ __launch_bounds__(256) void gemm_bb(
    const unsigned short* __restrict__ A, const unsigned short* __restrict__ Bw,
    const float* __restrict__ bias, void* __restrict__ Cptr,
    int M, int N, int K) {
  __shared__ short lds_a[128 * 64];
  __shared__ short lds_b[128 * 64];
  const int t = threadIdx.x;
  const int l = t & 63;
  const int w = t >> 6;
  const int id = blockIdx.x;
  const int xcd = id & 7;
  const int rr = id >> 3;
  const int bm = (xcd * 8 + (rr & 7)) * 128;
  const int bn = (rr >> 3) * 128;
  const int wr = (w >> 1) * 64;
  const int wc = (w & 1) * 64;
  const int lr = l & 15;
  const int lkh = l >> 4;          // 0..3

  f32x4 acc[4][4] = {};

  // staging: wave w rows [w*32, w*32+32), 4 chunks of 8 rows; lane l covers
  // row chunk_base + (l>>3), LDS col (l&7)*8 (linear), GLOBAL col pre-swizzled.
  const int c8 = l >> 3;                     // row-in-chunk = row&7
  const int gcol = ((l & 7) ^ c8) * 8;       // pre-swizzled source column

  for (int k0 = 0; k0 < K; k0 += 64) {
    const unsigned short* as = &A[(size_t)(bm + w * 32 + c8) * K + k0 + gcol];
    const unsigned short* bs = &Bw[(size_t)(bn + w * 32 + c8) * K + k0 + gcol];
#pragma unroll
    for (int c = 0; c < 4; ++c) {
      gload_lds16(as + (size_t)(c * 8) * K, &lds_a[(w * 32 + c * 8) * 64]);
      gload_lds16(bs + (size_t)(c * 8) * K, &lds_b[(w * 32 + c * 8) * 64]);
    }
    __syncthreads();

#pragma unroll
    for (int ki = 0; ki < 2; ++ki) {
      s16x8 af[4], bfr[4];
#pragma unroll
      for (int mt = 0; mt < 4; ++mt) {
        const int row = wr + mt * 16 + lr;
        af[mt] = *reinterpret_cast<const s16x8*>(
            &lds_a[row * 64 + ((((ki << 2) + lkh) ^ (lr & 7)) << 3)]);
      }
#pragma unroll
      for (int nt = 0; nt < 4; ++nt) {
        const int row = wc + nt * 16 + lr;
        bfr[nt] = *reinterpret_cast<const s16x8*>(
            &lds_b[row * 64 + ((((ki << 2) + lkh) ^ (lr & 7)) << 3)]);
      }
#pragma unroll
      for (int mt = 0; mt < 4; ++mt)
#pragma unroll
        for (int nt = 0; nt < 4; ++nt)
          acc[mt][nt] = __builtin_amdgcn_mfma_f32_16x16x32_bf16(af[mt], bfr[nt], acc[mt][nt], 0, 0, 0);
    }
    __syncthreads();
  }

  if (SCATTER) {
    // hoisted decode: col-derived (h, part, d, bh, stride, scale) are
    // mt/r-invariant; per-element address is one strength-reduced add.
    unsigned short* W = (unsigned short*)Cptr;
    const int s0 = (bm & 2047) + wr + (l >> 4) * 4;
    const int batch = bm >> 11;
#pragma unroll
    for (int nt = 0; nt < 4; ++nt) {
      const int col = bn + wc + nt * 16 + lr;
      const int h = col / 192;
      const int rem = col - h * 192;
      const int part = rem >> 6;          // 0=Q 1=K 2=V
      const int d = rem & 63;
      const size_t bh = (size_t)batch * 16 + h;
      const float bv = bias[col];
      unsigned short* base;
      int stride;
      float scale;
      if (part == 2) {
        base = W + 2 * PART_ELEMS + (bh * 64 + d) * 2048;   // VT[bh][d][s]
        stride = 1;
        scale = 1.0f;
      } else {
        base = W + (size_t)part * PART_ELEMS + bh * 2048 * 64 + d;  // Q/K[bh][s][d]
        stride = 64;
        scale = (part == 0) ? 0.1803368801f : 1.0f;         // 0.125*log2e on Q
      }
      unsigned short* p = base + (size_t)s0 * stride;
#pragma unroll
      for (int mt = 0; mt < 4; ++mt) {
        unsigned short* pm = p + mt * 16 * stride;
#pragma unroll
        for (int r = 0; r < 4; ++r)
          pm[r * stride] = f2bf((acc[mt][nt][r] + bv) * scale);
      }
    }
  } else {
    float* C = (float*)Cptr;
#pragma unroll
    for (int mt = 0; mt < 4; ++mt) {
#pragma unroll
      for (int nt = 0; nt < 4; ++nt) {
        const int col = bn + wc + nt * 16 + lr;
        const float bv = bias[col];
#pragma unroll
        for (int r = 0; r < 4; ++r) {
          const int row = bm + wr + mt * 16 + (l >> 4) * 4 + r;
          C[(size_t)row * N + col] = acc[mt][nt][r] + bv;
        }
      }
    }
  }
}

// Flash attention over planes Q[bh][s][64] (pre-scaled), K[bh][s][64], VT[bh][d][s].
// 8 waves/block, 256 q-rows (32/wave); KV tile 64, reg-staged double-buffer,
// ONE barrier per kt. XCD-local flat-grid decode. Swapped QK^T. NO-MAX softmax
// (shift-invariant; |s| << 60 -> no overflow), lane-local l partials reduced
// once in the epilogue. LDS 64 KB.
__global__ __launch_bounds__(512, 4) void attn_kernel(
    const unsigned short* __restrict__ ws, unsigned short* __restrict__ vals) {
  __shared__ short k_lds[2][64 * 64];
  __shared__ short vt_lds[2][64 * 64];
  __shared__ short p_lds[256 * 64];
  const int t = threadIdx.x;
  const int l = t & 63;
  const int w = t >> 6;            // 0..7
  const int lr = l & 15;
  const int lkh = l >> 4;
  const int f = blockIdx.x;        // 0..511
  const int xcd = f & 7;
  const int j = f >> 3;            // 0..63
  const int bh = xcd * 8 + (j & 7);
  const int qt = j >> 3;           // 0..7
  const int b = bh >> 4;
  const int h = bh & 15;
  const unsigned short* Qh  = ws + (size_t)bh * (2048 * 64);
  const unsigned short* Kh  = ws + PART_ELEMS + (size_t)bh * (2048 * 64);
  const unsigned short* VTh = ws + 2 * PART_ELEMS + (size_t)bh * (64 * 2048);

  const int srow = t >> 3;         // 0..63
  const int scol = (t & 7) * 8;    // 0..56

  s16x8 qf[2][2];
  {
    const unsigned short* qb = Qh + ((size_t)qt * 256 + w * 32 + lr) * 64 + lkh * 8;
    qf[0][0] = *reinterpret_cast<const s16x8*>(qb);
    qf[0][1] = *reinterpret_cast<const s16x8*>(qb + 32);
    qf[1][0] = *reinterpret_cast<const s16x8*>(qb + 16 * 64);
    qf[1][1] = *reinterpret_cast<const s16x8*>(qb + 16 * 64 + 32);
  }
  {
    s16x8 k0 = *reinterpret_cast<const s16x8*>(Kh + (size_t)srow * 64 + scol);
    s16x8 v0 = *reinterpret_cast<const s16x8*>(VTh + (size_t)srow * 2048 + scol);
    *reinterpret_cast<s16x8*>(&k_lds[0][swzs(srow, scol)])  = k0;
    *reinterpret_cast<s16x8*>(&vt_lds[0][swzs(srow, scol)]) = v0;
  }
  __syncthreads();

  f32x4 o_acc[2][4] = {};
  float l_s[2] = {0.f, 0.f};       // lane-local partial (deferred reduction)

  for (int kt = 0; kt < 32; ++kt) {
    const int cur = kt & 1;
    const int nxt = cur ^ 1;
    const bool pre = (kt + 1) < 32;

    s16x8 kr, vr;
    if (pre) {
      kr = *reinterpret_cast<const s16x8*>(Kh + ((size_t)(kt + 1) * 64 + srow) * 64 + scol);
      vr = *reinterpret_cast<const s16x8*>(VTh + (size_t)srow * 2048 + (kt + 1) * 64 + scol);
    }

    // ---- S^T = K Q^T (swapped); kf shared across both q-halves ----
    f32x4 s_acc[2][4] = {};
    {
      s16x8 kf[4][2];
#pragma unroll
      for (int nt = 0; nt < 4; ++nt) {
        kf[nt][0] = *reinterpret_cast<const s16x8*>(&k_lds[cur][swzs(nt * 16 + lr, lkh * 8)]);
        kf[nt][1] = *reinterpret_cast<const s16x8*>(&k_lds[cur][swzs(nt * 16 + lr, 32 + lkh * 8)]);
      }
      __builtin_amdgcn_s_setprio(1);
#pragma unroll
      for (int qh = 0; qh < 2; ++qh)
#pragma unroll
        for (int nt = 0; nt < 4; ++nt) {
          s_acc[qh][nt] = __builtin_amdgcn_mfma_f32_16x16x32_bf16(kf[nt][0], qf[qh][0], s_acc[qh][nt], 0, 0, 0);
          s_acc[qh][nt] = __builtin_amdgcn_mfma_f32_16x16x32_bf16(kf[nt][1], qf[qh][1], s_acc[qh][nt], 0, 0, 0);
        }
      __builtin_amdgcn_s_setprio(0);
    }

    // ---- NO-MAX softmax: P = exp2(s) straight; lane-local l partials ----
#pragma unroll
    for (int qh = 0; qh < 2; ++qh) {
      float rs = 0.f;
#pragma unroll
      for (int nt = 0; nt < 4; ++nt) {
        float p0 = fexp2(s_acc[qh][nt][0]);
        float p1 = fexp2(s_acc[qh][nt][1]);
        float p2 = fexp2(s_acc[qh][nt][2]);
        float p3 = fexp2(s_acc[qh][nt][3]);
        rs += (p0 + p1) + (p2 + p3);
        u32x2 pk;
        pk.x = pack2bf(p0, p1);
        pk.y = pack2bf(p2, p3);
        *reinterpret_cast<u32x2*>(&p_lds[swzs(w * 32 + qh * 16 + lr, nt * 16 + 4 * lkh)]) = pk;
      }
      l_s[qh] += rs;
    }

    // ---- O += P @ V; vf shared across both q-halves ----
    {
      s16x8 vf[4][2];
#pragma unroll
      for (int nt = 0; nt < 4; ++nt) {
        vf[nt][0] = *reinterpret_cast<const s16x8*>(&vt_lds[cur][swzs(nt * 16 + lr, lkh * 8)]);
        vf[nt][1] = *reinterpret_cast<const s16x8*>(&vt_lds[cur][swzs(nt * 16 + lr, 32 + lkh * 8)]);
      }
      __builtin_amdgcn_s_setprio(1);
#pragma unroll
      for (int qh = 0; qh < 2; ++qh) {
        s16x8 pf0 = *reinterpret_cast<const s16x8*>(&p_lds[swzs(w * 32 + qh * 16 + lr, lkh * 8)]);
        s16x8 pf1 = *reinterpret_cast<const s16x8*>(&p_lds[swzs(w * 32 + qh * 16 + lr, 32 + lkh * 8)]);
#pragma unroll
        for (int nt = 0; nt < 4; ++nt) {
          o_acc[qh][nt] = __builtin_amdgcn_mfma_f32_16x16x32_bf16(pf0, vf[nt][0], o_acc[qh][nt], 0, 0, 0);
          o_acc[qh][nt] = __builtin_amdgcn_mfma_f32_16x16x32_bf16(pf1, vf[nt][1], o_acc[qh][nt], 0, 0, 0);
        }
      }
      __builtin_amdgcn_s_setprio(0);
    }

    // ---- write next tiles into the other buffer; ONE barrier per kt ----
    if (pre) {
      *reinterpret_cast<s16x8*>(&k_lds[nxt][swzs(srow, scol)])  = kr;
      *reinterpret_cast<s16x8*>(&vt_lds[nxt][swzs(srow, scol)]) = vr;
    }
    __syncthreads();
  }

  // ---- deferred l reduction, then epilogue ----
#pragma unroll
  for (int qh = 0; qh < 2; ++qh) {
    l_s[qh] += __shfl_xor(l_s[qh], 16);
    l_s[qh] += __shfl_xor(l_s[qh], 32);
  }
#pragma unroll
  for (int qh = 0; qh < 2; ++qh) {
#pragma unroll
    for (int r = 0; r < 4; ++r) {
      const float lv = __shfl(l_s[qh], 4 * lkh + r);
      const float inv = 1.0f / lv;
      const size_t row = (size_t)b * 2048 + qt * 256 + w * 32 + qh * 16 + lkh * 4 + r;
#pragma unroll
      for (int nt = 0; nt < 4; ++nt) {
        vals[row * 1024 + h * 64 + nt * 16 + lr] = f2bf(o_acc[qh][nt][r] * inv);
      }
    }
  }
}

extern "C" void kernel_launch(void* const* d_in, const int* in_sizes, int n_in,
                              void* d_out, int out_size, void* d_ws, size_t ws_size,
                              hipStream_t stream) {
  const float* x     = (const float*)d_in[0];   // [4,2048,1024]
  const float* w_qkv = (const float*)d_in[1];   // [3072,1024]
  const float* b_qkv = (const float*)d_in[2];   // [3072]
  const float* w_o   = (const float*)d_in[3];   // [1024,1024]
  const float* b_o   = (const float*)d_in[4];   // [1024]
  float* out = (float*)d_out;                   // [4,2048,1024] fp32

  unsigned short* xb     = (unsigned short*)d_ws;   // x bf16; later: vals (aliased)
  unsigned short* planes = xb + PART_ELEMS;         // Q | K | VT planes
  unsigned short* wqkv_b = (unsigned short*)d_out;  // d_out scratch; only read by
                                                    // gemm1 (d_out untouched until gemm3)
  unsigned short* wo_b   = planes;                  // Q-plane, dead after attn

  cvt2_kernel<<<5632, 256, 0, stream>>>(x, xb, w_qkv, wqkv_b);      // x + w_qkv -> bf16
  gemm_bb<true><<<1536, 256, 0, stream>>>(
      xb, wqkv_b, b_qkv, planes, 8192, 3072, 1024);                 // qkv + scatter
  attn_kernel<<<512, 512, 0, stream>>>(planes, xb);                 // vals -> xb
  cvt_kernel<<<512, 256, 0, stream>>>(w_o, wo_b);                   // w_o -> bf16 (Q-plane)
  gemm_bb<false><<<512, 256, 0, stream>>>(
      xb, wo_b, b_o, out, 8192, 1024, 1024);                        // out proj
}